// Round 7
// baseline (405.010 us; speedup 1.0000x reference)
//
#include <hip/hip_runtime.h>
#include <math.h>

#define D 64
#define NEG_SLOPE 0.2f
#define TILE 8192  // edges per partition block

__device__ __forceinline__ float lrelu(float x) { return x > 0.f ? x : NEG_SLOPE * x; }

// fp32 -> bf16 with round-to-nearest-even (manual; no NaN inputs here).
__device__ __forceinline__ unsigned short f2bf(float f) {
    unsigned u = __float_as_uint(f);
    return (unsigned short)((u + 0x7fffu + ((u >> 16) & 1u)) >> 16);
}
// unpack 2 bf16 (packed lo,hi in a uint) -> float2
__device__ __forceinline__ float2 bf2f2(unsigned u) {
    float2 r;
    r.x = __uint_as_float(u << 16);
    r.y = __uint_as_float(u & 0xffff0000u);
    return r;
}

// Tiled register-blocked GEMM: h_bf16 = bf16(x @ W), fused alpha dot products.
// h is ONLY consumed by the aggregate gather -> store bf16 (halves gather bytes).
__global__ __launch_bounds__(256, 4) void gemm_alpha(
    const float* __restrict__ x, const float* __restrict__ W,
    const float* __restrict__ a_src, const float* __restrict__ a_dst,
    unsigned short* __restrict__ hb, float* __restrict__ asrc,
    float* __restrict__ adst, int N) {
    __shared__ float xs[64][68];
    __shared__ float Ws[64][68];
    const int tid = threadIdx.x;
    const int r0 = blockIdx.x * 64;

    for (int i = tid; i < 4096; i += 256) {
        int k = i >> 6, c = i & 63;
        Ws[k][c] = W[i];
    }
    for (int i = tid; i < 4096; i += 256) {
        int r = i >> 6, k = i & 63;
        int gr = r0 + r;
        xs[r][k] = (gr < N) ? x[(size_t)gr * D + k] : 0.f;
    }
    __syncthreads();

    const int tx = tid & 15;
    const int ty = tid >> 4;
    float acc[4][4] = {};
#pragma unroll 4
    for (int k = 0; k < 64; k += 4) {
        float xr[4][4], wc[4][4];
#pragma unroll
        for (int i = 0; i < 4; ++i)
            *(float4*)xr[i] = *(const float4*)&xs[ty * 4 + i][k];
#pragma unroll
        for (int u = 0; u < 4; ++u)
            *(float4*)wc[u] = *(const float4*)&Ws[k + u][tx * 4];
#pragma unroll
        for (int i = 0; i < 4; ++i)
#pragma unroll
            for (int j = 0; j < 4; ++j)
#pragma unroll
                for (int u = 0; u < 4; ++u)
                    acc[i][j] = fmaf(xr[i][u], wc[u][j], acc[i][j]);
    }

#pragma unroll
    for (int i = 0; i < 4; ++i) {
        int gr = r0 + ty * 4 + i;
        if (gr < N) {
            uint2 p;
            p.x = (unsigned)f2bf(acc[i][0]) | ((unsigned)f2bf(acc[i][1]) << 16);
            p.y = (unsigned)f2bf(acc[i][2]) | ((unsigned)f2bf(acc[i][3]) << 16);
            *(uint2*)&hb[(size_t)gr * D + tx * 4] = p;
        }
    }
    float as4[4], ad4[4];
    *(float4*)as4 = *(const float4*)&a_src[tx * 4];
    *(float4*)ad4 = *(const float4*)&a_dst[tx * 4];
#pragma unroll
    for (int i = 0; i < 4; ++i) {
        float ps = 0.f, pd = 0.f;
#pragma unroll
        for (int j = 0; j < 4; ++j) {
            ps = fmaf(acc[i][j], as4[j], ps);
            pd = fmaf(acc[i][j], ad4[j], pd);
        }
#pragma unroll
        for (int off = 1; off < 16; off <<= 1) {
            ps += __shfl_xor(ps, off);
            pd += __shfl_xor(pd, off);
        }
        if (tx == 0) {
            int gr = r0 + ty * 4 + i;
            if (gr < N) { asrc[gr] = ps; adst[gr] = pd; }
        }
    }
}

// Pass A.1: per-tile histogram over coarse buckets (d>>9). mat[b*nblkA + blk] = count.
__global__ void histA(const int* __restrict__ dst, int* __restrict__ mat,
                      int E, int nblkA, int NBc) {
    __shared__ int cnt[256];
    cnt[threadIdx.x] = 0;
    __syncthreads();
    const int base = blockIdx.x * TILE;
    for (int j = threadIdx.x; j < TILE; j += 256) {
        int i = base + j;
        if (i < E) atomicAdd(&cnt[dst[i] >> 9], 1);
    }
    __syncthreads();
    for (int b = threadIdx.x; b < NBc; b += 256) mat[b * nblkA + blockIdx.x] = cnt[b];
}

// Pass A.2: single-block exclusive scan of mat[0..M) in place (bucket-major).
__global__ void matscan(int* __restrict__ mat, int M) {
    __shared__ int wsum[16];
    __shared__ int ctot;
    const int lane = threadIdx.x & 63, wid = threadIdx.x >> 6;  // 1024 threads
    int running = 0;
    for (int base = 0; base < M; base += 1024) {
        int i = base + (int)threadIdx.x;
        int v = (i < M) ? mat[i] : 0;
        int x = v;
#pragma unroll
        for (int off = 1; off < 64; off <<= 1) {
            int y = __shfl_up(x, off);
            if (lane >= off) x += y;
        }
        if (lane == 63) wsum[wid] = x;
        __syncthreads();
        if (wid == 0) {
            int ws = (lane < 16) ? wsum[lane] : 0;
#pragma unroll
            for (int off = 1; off < 16; off <<= 1) {
                int y = __shfl_up(ws, off);
                if (lane >= off) ws += y;
            }
            if (lane < 16) wsum[lane] = ws;
            if (lane == 15) ctot = ws;
        }
        __syncthreads();
        int woff = (wid == 0) ? 0 : wsum[wid - 1];
        if (i < M) mat[i] = running + woff + (x - v);
        running += ctot;
        __syncthreads();
    }
}

// Pass A.3: replay tile; write packed (dlow<<17 | src) into this block's contiguous
// allocation per bucket (LDS cursors seeded from scanned mat column).
__global__ void scatterA(const int* __restrict__ src, const int* __restrict__ dst,
                         const int* __restrict__ mat, unsigned* __restrict__ tmp,
                         int E, int nblkA, int NBc) {
    __shared__ int cur[256];
    for (int b = threadIdx.x; b < NBc; b += 256) cur[b] = mat[b * nblkA + blockIdx.x];
    __syncthreads();
    const int base = blockIdx.x * TILE;
    for (int j = threadIdx.x; j < TILE; j += 256) {
        int i = base + j;
        if (i < E) {
            int d = dst[i];
            int pos = atomicAdd(&cur[d >> 9], 1);
            tmp[pos] = ((unsigned)(d & 511) << 17) | (unsigned)src[i];
        }
    }
}

// Pass B: one block per coarse bucket. Builds row[] and places src ids into csr.
__global__ void bucket_build(const int* __restrict__ mat, const unsigned* __restrict__ tmp,
                             int* __restrict__ row, int* __restrict__ csr,
                             int N, int E, int nblkA, int NBc) {
    __shared__ int cnt[512];
    __shared__ int wsum[4];
    const int b = blockIdx.x;
    const int n0 = b << 9;
    const int tid = threadIdx.x;
    const int beg = mat[b * nblkA];
    const int end = (b + 1 < NBc) ? mat[(b + 1) * nblkA] : E;
    cnt[tid] = 0;
    cnt[tid + 256] = 0;
    __syncthreads();
    for (int i = beg + tid; i < end; i += 256) atomicAdd(&cnt[tmp[i] >> 17], 1);
    __syncthreads();
    const int c0 = cnt[2 * tid], c1 = cnt[2 * tid + 1];
    const int ts = c0 + c1;
    int x = ts;
#pragma unroll
    for (int off = 1; off < 64; off <<= 1) {
        int y = __shfl_up(x, off);
        if ((tid & 63) >= off) x += y;
    }
    if ((tid & 63) == 63) wsum[tid >> 6] = x;
    __syncthreads();
    int woff = 0;
    for (int w = 0; w < (tid >> 6); ++w) woff += wsum[w];
    const int ex = beg + woff + x - ts;
    const int na = n0 + 2 * tid, nb2 = n0 + 2 * tid + 1;
    if (na < N) row[na] = ex;
    if (nb2 < N) row[nb2] = ex + c0;
    if (b == NBc - 1 && tid == 0) row[N] = E;
    cnt[2 * tid] = ex;
    cnt[2 * tid + 1] = ex + c0;
    __syncthreads();
    for (int i = beg + tid; i < end; i += 256) {
        unsigned e = tmp[i];
        int pos = atomicAdd(&cnt[e >> 17], 1);
        csr[pos] = (int)(e & 0x1FFFFu);
    }
}

// One wave per dst node, single pass, bf16 h gather.
// 8 lane-groups x 8 lanes: group g processes edges j*8+g; each lane loads 16 B
// (8 bf16 features). fp32 accumulate; softmax needs no max shift (logits O(10)).
__global__ void aggregate(const int* __restrict__ row, const int* __restrict__ csr_src,
                          const float* __restrict__ asrc, const float* __restrict__ adst,
                          const unsigned short* __restrict__ hb, const float* __restrict__ b,
                          float* __restrict__ out, int N, int do_elu) {
    const int wave = threadIdx.x >> 6, lane = threadIdx.x & 63;
    const int d = blockIdx.x * 4 + wave;
    if (d >= N) return;
    const int g = lane >> 3, c = lane & 7;  // group, 16B feature slot
    const int beg = row[d], end = row[d + 1];
    const float ad = adst[d];
    const float w_self = __expf(lrelu(asrc[d] + ad));

    float acc[8] = {};
    float dnp = (lane == 0) ? w_self : 0.f;
    if (g == 0) {
        const uint4 hv = *(const uint4*)&hb[(size_t)d * D + c * 8];
        float2 p;
        p = bf2f2(hv.x); acc[0] = w_self * p.x; acc[1] = w_self * p.y;
        p = bf2f2(hv.y); acc[2] = w_self * p.x; acc[3] = w_self * p.y;
        p = bf2f2(hv.z); acc[4] = w_self * p.x; acc[5] = w_self * p.y;
        p = bf2f2(hv.w); acc[6] = w_self * p.x; acc[7] = w_self * p.y;
    }

    for (int base = beg; base < end; base += 64) {
        const int i = base + lane;
        int s = d;
        float w = 0.f;
        if (i < end) {
            s = csr_src[i];
            w = __expf(lrelu(asrc[s] + ad));
        }
        dnp += w;
        const int cnt = min(64, end - base);
        const int ng = (cnt + 7) >> 3;  // 8-edge groups this chunk
        for (int j = 0; j < ng; ++j) {
            const int idx = j * 8 + g;           // padded slots: s=d, w=0 (safe)
            const int sj = __shfl(s, idx);
            const float wj = __shfl(w, idx);
            const uint4 hv = *(const uint4*)&hb[(size_t)sj * D + c * 8];
            float2 p;
            p = bf2f2(hv.x); acc[0] = fmaf(wj, p.x, acc[0]); acc[1] = fmaf(wj, p.y, acc[1]);
            p = bf2f2(hv.y); acc[2] = fmaf(wj, p.x, acc[2]); acc[3] = fmaf(wj, p.y, acc[3]);
            p = bf2f2(hv.z); acc[4] = fmaf(wj, p.x, acc[4]); acc[5] = fmaf(wj, p.y, acc[5]);
            p = bf2f2(hv.w); acc[6] = fmaf(wj, p.x, acc[6]); acc[7] = fmaf(wj, p.y, acc[7]);
        }
    }

    // reduce the 8 lane-groups (xor 8,16,32); denom across all 64 lanes
#pragma unroll
    for (int off = 8; off < 64; off <<= 1)
#pragma unroll
        for (int k = 0; k < 8; ++k) acc[k] += __shfl_xor(acc[k], off);
#pragma unroll
    for (int off = 1; off < 64; off <<= 1) dnp += __shfl_xor(dnp, off);

    if (g == 0) {
        const float inv = 1.f / dnp;
        float v[8];
#pragma unroll
        for (int k = 0; k < 8; ++k) {
            v[k] = fmaf(acc[k], inv, b[c * 8 + k]);
            if (do_elu) v[k] = v[k] > 0.f ? v[k] : expm1f(v[k]);
        }
        *(float4*)&out[(size_t)d * D + c * 8]     = *(float4*)&v[0];
        *(float4*)&out[(size_t)d * D + c * 8 + 4] = *(float4*)&v[4];
    }
}

extern "C" void kernel_launch(void* const* d_in, const int* in_sizes, int n_in,
                              void* d_out, int out_size, void* d_ws, size_t ws_size,
                              hipStream_t stream) {
    const int*   eidx = (const int*)d_in[0];
    const float* emb  = (const float*)d_in[1];
    const float* W1   = (const float*)d_in[2];
    const float* a1s  = (const float*)d_in[3];
    const float* a1d  = (const float*)d_in[4];
    const float* b1   = (const float*)d_in[5];
    const float* W2   = (const float*)d_in[6];
    const float* a2s  = (const float*)d_in[7];
    const float* a2d  = (const float*)d_in[8];
    const float* b2   = (const float*)d_in[9];
    float* out = (float*)d_out;

    const int E = in_sizes[0] / 2;
    const int N = in_sizes[1] / D;  // requires N <= 131072 (17-bit src packing)
    const int* src = eidx;
    const int* dst = eidx + E;

    const int nblkA = (E + TILE - 1) / TILE;   // partition blocks
    const int NBc   = (N + 511) / 512;         // coarse buckets (<=256)

    // Workspace: hb [N*D bf16 = N*D/2 floats], x1 [N*D], asrc/adst [N], row [N+1],
    // mat [NBc*nblkA], csr [E]. tmp [E] aliases x1 (dead until layer-1 aggregate).
    float* ws   = (float*)d_ws;
    unsigned short* hb = (unsigned short*)ws;            // N*D bf16
    float* x1   = ws + (size_t)N * D / 2;                // N*D fp32
    float* asrc = x1 + (size_t)N * D;
    float* adst = asrc + N;
    int* row    = (int*)(adst + N);
    int* mat    = row + N + 1;
    int* csr    = mat + (size_t)NBc * nblkA;
    unsigned* tmp = (unsigned*)x1;

    const int gemmBlocks = (N + 63) / 64;
    const int nodeBlocks = (N + 3) / 4;

    // ---- CSR build ----
    histA<<<nblkA, 256, 0, stream>>>(dst, mat, E, nblkA, NBc);
    matscan<<<1, 1024, 0, stream>>>(mat, NBc * nblkA);
    scatterA<<<nblkA, 256, 0, stream>>>(src, dst, mat, tmp, E, nblkA, NBc);
    bucket_build<<<NBc, 256, 0, stream>>>(mat, tmp, row, csr, N, E, nblkA, NBc);

    // ---- Layer 1 ----
    gemm_alpha<<<gemmBlocks, 256, 0, stream>>>(emb, W1, a1s, a1d, hb, asrc, adst, N);
    aggregate<<<nodeBlocks, 256, 0, stream>>>(row, csr, asrc, adst, hb, b1, x1, N, 1);

    // ---- Layer 2 ----
    gemm_alpha<<<gemmBlocks, 256, 0, stream>>>(x1, W2, a2s, a2d, hb, asrc, adst, N);
    aggregate<<<nodeBlocks, 256, 0, stream>>>(row, csr, asrc, adst, hb, b2, out, N, 0);
}

// Round 8
// 294.405 us; speedup vs baseline: 1.3757x; 1.3757x over previous
//
#include <hip/hip_runtime.h>
#include <math.h>

#define D 64
#define NEG_SLOPE 0.2f
#define TILE 4096   // edges per partition block (391 blocks at E=1.6M)
#define BKT 128     // nodes per coarse bucket (782 build blocks)

__device__ __forceinline__ float lrelu(float x) { return fmaxf(x, NEG_SLOPE * x); }

// fp32 -> bf16 round-to-nearest-even.
__device__ __forceinline__ unsigned short f2bf(float f) {
    unsigned u = __float_as_uint(f);
    return (unsigned short)((u + 0x7fffu + ((u >> 16) & 1u)) >> 16);
}
__device__ __forceinline__ float2 bf2f2(unsigned u) {
    float2 r;
    r.x = __uint_as_float(u << 16);
    r.y = __uint_as_float(u & 0xffff0000u);
    return r;
}

// Tiled register-blocked GEMM: h_bf16 = bf16(x @ W), fused alpha dot products.
__global__ __launch_bounds__(256, 4) void gemm_alpha(
    const float* __restrict__ x, const float* __restrict__ W,
    const float* __restrict__ a_src, const float* __restrict__ a_dst,
    unsigned short* __restrict__ hb, float* __restrict__ asrc,
    float* __restrict__ adst, int N) {
    __shared__ float xs[64][68];
    __shared__ float Ws[64][68];
    const int tid = threadIdx.x;
    const int r0 = blockIdx.x * 64;

    for (int i = tid; i < 4096; i += 256) {
        int k = i >> 6, c = i & 63;
        Ws[k][c] = W[i];
    }
    for (int i = tid; i < 4096; i += 256) {
        int r = i >> 6, k = i & 63;
        int gr = r0 + r;
        xs[r][k] = (gr < N) ? x[(size_t)gr * D + k] : 0.f;
    }
    __syncthreads();

    const int tx = tid & 15;
    const int ty = tid >> 4;
    float acc[4][4] = {};
#pragma unroll 4
    for (int k = 0; k < 64; k += 4) {
        float xr[4][4], wc[4][4];
#pragma unroll
        for (int i = 0; i < 4; ++i)
            *(float4*)xr[i] = *(const float4*)&xs[ty * 4 + i][k];
#pragma unroll
        for (int u = 0; u < 4; ++u)
            *(float4*)wc[u] = *(const float4*)&Ws[k + u][tx * 4];
#pragma unroll
        for (int i = 0; i < 4; ++i)
#pragma unroll
            for (int j = 0; j < 4; ++j)
#pragma unroll
                for (int u = 0; u < 4; ++u)
                    acc[i][j] = fmaf(xr[i][u], wc[u][j], acc[i][j]);
    }

#pragma unroll
    for (int i = 0; i < 4; ++i) {
        int gr = r0 + ty * 4 + i;
        if (gr < N) {
            uint2 p;
            p.x = (unsigned)f2bf(acc[i][0]) | ((unsigned)f2bf(acc[i][1]) << 16);
            p.y = (unsigned)f2bf(acc[i][2]) | ((unsigned)f2bf(acc[i][3]) << 16);
            *(uint2*)&hb[(size_t)gr * D + tx * 4] = p;
        }
    }
    float as4[4], ad4[4];
    *(float4*)as4 = *(const float4*)&a_src[tx * 4];
    *(float4*)ad4 = *(const float4*)&a_dst[tx * 4];
#pragma unroll
    for (int i = 0; i < 4; ++i) {
        float ps = 0.f, pd = 0.f;
#pragma unroll
        for (int j = 0; j < 4; ++j) {
            ps = fmaf(acc[i][j], as4[j], ps);
            pd = fmaf(acc[i][j], ad4[j], pd);
        }
#pragma unroll
        for (int off = 1; off < 16; off <<= 1) {
            ps += __shfl_xor(ps, off);
            pd += __shfl_xor(pd, off);
        }
        if (tx == 0) {
            int gr = r0 + ty * 4 + i;
            if (gr < N) { asrc[gr] = ps; adst[gr] = pd; }
        }
    }
}

// A.1: per-tile histogram over coarse buckets (d>>7). mat[b*nblkA + blk] = count.
__global__ void histA(const int* __restrict__ dst, int* __restrict__ mat,
                      int E, int nblkA, int NBc) {
    __shared__ int cnt[1024];
    for (int b = threadIdx.x; b < NBc; b += 256) cnt[b] = 0;
    __syncthreads();
    const int base = blockIdx.x * TILE;
    for (int j = threadIdx.x; j < TILE; j += 256) {
        int i = base + j;
        if (i < E) atomicAdd(&cnt[dst[i] >> 7], 1);
    }
    __syncthreads();
    for (int b = threadIdx.x; b < NBc; b += 256) mat[b * nblkA + blockIdx.x] = cnt[b];
}

// A.2: hierarchical exclusive scan of mat[0..M) in place (bucket-major).
__global__ void scan_part1(const int* __restrict__ a, int* __restrict__ bsum, int M) {
    __shared__ int s[4];
    const int lane = threadIdx.x & 63, wid = threadIdx.x >> 6;
    int base = blockIdx.x * 1024;
    int v = 0;
    for (int j = threadIdx.x; j < 1024; j += 256) {
        int i = base + j;
        v += (i < M) ? a[i] : 0;
    }
#pragma unroll
    for (int off = 32; off; off >>= 1) v += __shfl_xor(v, off);
    if (lane == 0) s[wid] = v;
    __syncthreads();
    if (threadIdx.x == 0) bsum[blockIdx.x] = s[0] + s[1] + s[2] + s[3];
}
__global__ void scan_part2(int* __restrict__ bsum, int nb) {
    const int lane = threadIdx.x;  // 64 threads
    int running = 0;
    for (int base = 0; base < nb; base += 64) {
        int i = base + lane;
        int v = (i < nb) ? bsum[i] : 0;
        int x = v;
#pragma unroll
        for (int off = 1; off < 64; off <<= 1) {
            int y = __shfl_up(x, off);
            if (lane >= off) x += y;
        }
        if (i < nb) bsum[i] = running + x - v;
        running += __shfl(x, 63);
    }
}
__global__ void scan_part3(int* __restrict__ a, const int* __restrict__ bsum, int M) {
    __shared__ int wsum[4];
    const int lane = threadIdx.x & 63, wid = threadIdx.x >> 6;
    const int i0 = blockIdx.x * 1024 + (int)threadIdx.x * 4;
    int v[4];
#pragma unroll
    for (int u = 0; u < 4; ++u) v[u] = (i0 + u < M) ? a[i0 + u] : 0;
    int tsum = v[0] + v[1] + v[2] + v[3];
    int incl = tsum;
#pragma unroll
    for (int off = 1; off < 64; off <<= 1) {
        int y = __shfl_up(incl, off);
        if (lane >= off) incl += y;
    }
    if (lane == 63) wsum[wid] = incl;
    __syncthreads();
    int woff = 0;
    for (int w = 0; w < wid; ++w) woff += wsum[w];
    int ex = bsum[blockIdx.x] + woff + incl - tsum;
#pragma unroll
    for (int u = 0; u < 4; ++u) {
        if (i0 + u < M) a[i0 + u] = ex;
        ex += v[u];
    }
}

// A.3: replay tile; write packed (d&127)<<17 | src into this block's contiguous
// per-bucket allocation (LDS cursors from scanned mat column).
__global__ void scatterA(const int* __restrict__ src, const int* __restrict__ dst,
                         const int* __restrict__ mat, unsigned* __restrict__ tmp,
                         int E, int nblkA, int NBc) {
    __shared__ int cur[1024];
    for (int b = threadIdx.x; b < NBc; b += 256) cur[b] = mat[b * nblkA + blockIdx.x];
    __syncthreads();
    const int base = blockIdx.x * TILE;
    for (int j = threadIdx.x; j < TILE; j += 256) {
        int i = base + j;
        if (i < E) {
            int d = dst[i];
            int pos = atomicAdd(&cur[d >> 7], 1);
            tmp[pos] = ((unsigned)(d & (BKT - 1)) << 17) | (unsigned)src[i];
        }
    }
}

// B: one block per coarse bucket (128 nodes). Builds row[] and places src into csr.
__global__ void bucket_build(const int* __restrict__ mat, const unsigned* __restrict__ tmp,
                             int* __restrict__ row, int* __restrict__ csr,
                             int N, int E, int nblkA, int NBc) {
    __shared__ int cnt[BKT];
    __shared__ int cur[BKT];
    __shared__ int wsumS[2];
    const int b = blockIdx.x;
    const int n0 = b << 7;
    const int tid = threadIdx.x;
    const int beg = mat[b * nblkA];
    const int end = (b + 1 < NBc) ? mat[(b + 1) * nblkA] : E;
    if (tid < BKT) cnt[tid] = 0;
    __syncthreads();
    for (int i = beg + tid; i < end; i += 256) atomicAdd(&cnt[tmp[i] >> 17], 1);
    __syncthreads();
    int v = (tid < BKT) ? cnt[tid] : 0;
    int x = v;
#pragma unroll
    for (int off = 1; off < 64; off <<= 1) {
        int y = __shfl_up(x, off);
        if ((tid & 63) >= off) x += y;
    }
    if (tid < BKT && (tid & 63) == 63) wsumS[tid >> 6] = x;
    __syncthreads();
    const int add = (tid >= 64 && tid < BKT) ? wsumS[0] : 0;
    const int ex = beg + add + x - v;
    if (tid < BKT) {
        const int node = n0 + tid;
        if (node < N) row[node] = ex;
        cur[tid] = ex;
    }
    if (b == NBc - 1 && tid == 0) row[N] = E;
    __syncthreads();
    for (int i = beg + tid; i < end; i += 256) {
        unsigned e = tmp[i];
        int pos = atomicAdd(&cur[e >> 17], 1);
        csr[pos] = (int)(e & 0x1FFFFu);
    }
}

// Aggregate: one node per 8-lane group (8 nodes/wave, 32/block). Lane owns 8
// features (one uint4 of bf16). Group-uniform csr/asrc loads (HW broadcast),
// weight computed once per edge, dnp replicated per-lane -> NO cross-lane
// reductions, NO shfl broadcasts. fp32 accumulate; no max shift (logits O(10)).
__global__ __launch_bounds__(256) void aggregate(
    const int* __restrict__ row, const int* __restrict__ csr_src,
    const float* __restrict__ asrc, const float* __restrict__ adst,
    const unsigned short* __restrict__ hb, const float* __restrict__ bias,
    float* __restrict__ out, int N, int do_elu) {
    const int g = threadIdx.x >> 3;  // node-group within block
    const int c = threadIdx.x & 7;   // feature octet
    const int d = blockIdx.x * 32 + g;
    if (d >= N) return;
    const int beg = row[d], end = row[d + 1];
    const float ad = adst[d];
    float dnp = __expf(lrelu(asrc[d] + ad));  // self weight (identical in all 8 lanes)

    const unsigned short* hrow = hb + (c << 3);  // lane's 16B slot within any row
    float acc[8];
    {
        const uint4 hv = *(const uint4*)(hrow + ((unsigned)d << 6));
        float2 p;
        p = bf2f2(hv.x); acc[0] = dnp * p.x; acc[1] = dnp * p.y;
        p = bf2f2(hv.y); acc[2] = dnp * p.x; acc[3] = dnp * p.y;
        p = bf2f2(hv.z); acc[4] = dnp * p.x; acc[5] = dnp * p.y;
        p = bf2f2(hv.w); acc[6] = dnp * p.x; acc[7] = dnp * p.y;
    }

    int i = beg;
    for (; i + 2 <= end; i += 2) {
        const int s0 = csr_src[i], s1 = csr_src[i + 1];
        const float a0 = asrc[s0], a1 = asrc[s1];
        const uint4 h0 = *(const uint4*)(hrow + ((unsigned)s0 << 6));
        const uint4 h1 = *(const uint4*)(hrow + ((unsigned)s1 << 6));
        const float w0 = __expf(lrelu(a0 + ad));
        const float w1 = __expf(lrelu(a1 + ad));
        dnp += w0 + w1;
        float2 p;
        p = bf2f2(h0.x); acc[0] = fmaf(w0, p.x, acc[0]); acc[1] = fmaf(w0, p.y, acc[1]);
        p = bf2f2(h0.y); acc[2] = fmaf(w0, p.x, acc[2]); acc[3] = fmaf(w0, p.y, acc[3]);
        p = bf2f2(h0.z); acc[4] = fmaf(w0, p.x, acc[4]); acc[5] = fmaf(w0, p.y, acc[5]);
        p = bf2f2(h0.w); acc[6] = fmaf(w0, p.x, acc[6]); acc[7] = fmaf(w0, p.y, acc[7]);
        p = bf2f2(h1.x); acc[0] = fmaf(w1, p.x, acc[0]); acc[1] = fmaf(w1, p.y, acc[1]);
        p = bf2f2(h1.y); acc[2] = fmaf(w1, p.x, acc[2]); acc[3] = fmaf(w1, p.y, acc[3]);
        p = bf2f2(h1.z); acc[4] = fmaf(w1, p.x, acc[4]); acc[5] = fmaf(w1, p.y, acc[5]);
        p = bf2f2(h1.w); acc[6] = fmaf(w1, p.x, acc[6]); acc[7] = fmaf(w1, p.y, acc[7]);
    }
    if (i < end) {
        const int s0 = csr_src[i];
        const float w0 = __expf(lrelu(asrc[s0] + ad));
        const uint4 h0 = *(const uint4*)(hrow + ((unsigned)s0 << 6));
        dnp += w0;
        float2 p;
        p = bf2f2(h0.x); acc[0] = fmaf(w0, p.x, acc[0]); acc[1] = fmaf(w0, p.y, acc[1]);
        p = bf2f2(h0.y); acc[2] = fmaf(w0, p.x, acc[2]); acc[3] = fmaf(w0, p.y, acc[3]);
        p = bf2f2(h0.z); acc[4] = fmaf(w0, p.x, acc[4]); acc[5] = fmaf(w0, p.y, acc[5]);
        p = bf2f2(h0.w); acc[6] = fmaf(w0, p.x, acc[6]); acc[7] = fmaf(w0, p.y, acc[7]);
    }

    const float inv = 1.f / dnp;
    const float4 b0 = *(const float4*)&bias[c << 3];
    const float4 b1 = *(const float4*)&bias[(c << 3) + 4];
    float v[8];
    v[0] = fmaf(acc[0], inv, b0.x); v[1] = fmaf(acc[1], inv, b0.y);
    v[2] = fmaf(acc[2], inv, b0.z); v[3] = fmaf(acc[3], inv, b0.w);
    v[4] = fmaf(acc[4], inv, b1.x); v[5] = fmaf(acc[5], inv, b1.y);
    v[6] = fmaf(acc[6], inv, b1.z); v[7] = fmaf(acc[7], inv, b1.w);
    if (do_elu) {
#pragma unroll
        for (int k = 0; k < 8; ++k) v[k] = v[k] > 0.f ? v[k] : expm1f(v[k]);
    }
    *(float4*)&out[((size_t)d << 6) + (c << 3)]     = *(float4*)&v[0];
    *(float4*)&out[((size_t)d << 6) + (c << 3) + 4] = *(float4*)&v[4];
}

extern "C" void kernel_launch(void* const* d_in, const int* in_sizes, int n_in,
                              void* d_out, int out_size, void* d_ws, size_t ws_size,
                              hipStream_t stream) {
    const int*   eidx = (const int*)d_in[0];
    const float* emb  = (const float*)d_in[1];
    const float* W1   = (const float*)d_in[2];
    const float* a1s  = (const float*)d_in[3];
    const float* a1d  = (const float*)d_in[4];
    const float* b1   = (const float*)d_in[5];
    const float* W2   = (const float*)d_in[6];
    const float* a2s  = (const float*)d_in[7];
    const float* a2d  = (const float*)d_in[8];
    const float* b2   = (const float*)d_in[9];
    float* out = (float*)d_out;

    const int E = in_sizes[0] / 2;
    const int N = in_sizes[1] / D;  // requires N <= 131072 (17-bit src packing)
    const int* src = eidx;
    const int* dst = eidx + E;

    const int nblkA = (E + TILE - 1) / TILE;      // 391 partition blocks
    const int NBc   = (N + BKT - 1) / BKT;        // 782 coarse buckets
    const int M     = NBc * nblkA;                // scan length
    const int nscan = (M + 1023) / 1024;

    // Workspace: hb [N*D bf16], x1 [N*D f32], asrc/adst [N], row [N+1],
    // mat [M], msum [nscan], csr [E]. tmp [E] aliases x1.
    float* ws   = (float*)d_ws;
    unsigned short* hb = (unsigned short*)ws;       // N*D bf16
    float* x1   = ws + (size_t)N * D / 2;
    float* asrc = x1 + (size_t)N * D;
    float* adst = asrc + N;
    int* row    = (int*)(adst + N);
    int* mat    = row + N + 1;
    int* msum   = mat + M;
    int* csr    = msum + nscan;
    unsigned* tmp = (unsigned*)x1;  // CSR build completes before x1 is written

    const int gemmBlocks = (N + 63) / 64;
    const int aggBlocks  = (N + 31) / 32;

    // ---- CSR build ----
    histA<<<nblkA, 256, 0, stream>>>(dst, mat, E, nblkA, NBc);
    scan_part1<<<nscan, 256, 0, stream>>>(mat, msum, M);
    scan_part2<<<1, 64, 0, stream>>>(msum, nscan);
    scan_part3<<<nscan, 256, 0, stream>>>(mat, msum, M);
    scatterA<<<nblkA, 256, 0, stream>>>(src, dst, mat, tmp, E, nblkA, NBc);
    bucket_build<<<NBc, 256, 0, stream>>>(mat, tmp, row, csr, N, E, nblkA, NBc);

    // ---- Layer 1 ----
    gemm_alpha<<<gemmBlocks, 256, 0, stream>>>(emb, W1, a1s, a1d, hb, asrc, adst, N);
    aggregate<<<aggBlocks, 256, 0, stream>>>(row, csr, asrc, adst, hb, b1, x1, N, 1);

    // ---- Layer 2 ----
    gemm_alpha<<<gemmBlocks, 256, 0, stream>>>(x1, W2, a2s, a2d, hb, asrc, adst, N);
    aggregate<<<aggBlocks, 256, 0, stream>>>(row, csr, asrc, adst, hb, b2, out, N, 0);
}

// Round 9
// 267.474 us; speedup vs baseline: 1.5142x; 1.1007x over previous
//
#include <hip/hip_runtime.h>
#include <math.h>

#define D 64
#define NEG_SLOPE 0.2f
#define TILE 4096   // edges per partition block
#define BKT 128     // nodes per coarse bucket
#define LDK 72      // padded k-stride (bf16 elems) for MFMA LDS tiles
#define LDC 72      // padded col-stride (fp32) for epilogue C tile

typedef __attribute__((ext_vector_type(8))) short bf16x8;
typedef __attribute__((ext_vector_type(4))) float f32x4;

__device__ __forceinline__ float lrelu(float x) { return fmaxf(x, NEG_SLOPE * x); }

// fp32 -> bf16 round-to-nearest-even.
__device__ __forceinline__ unsigned short f2bf(float f) {
    unsigned u = __float_as_uint(f);
    return (unsigned short)((u + 0x7fffu + ((u >> 16) & 1u)) >> 16);
}
__device__ __forceinline__ float2 bf2f2(unsigned u) {
    float2 r;
    r.x = __uint_as_float(u << 16);
    r.y = __uint_as_float(u & 0xffff0000u);
    return r;
}

// MFMA bf16 GEMM: h_bf16 = bf16(x @ W) + fused alpha_src/alpha_dst dot products.
// Block: 64 rows x 64 cols, 4 waves; wave w owns rows w*16..+15 (4 n-tiles x K=64).
// A-frag: A[m=lane&15][k=quad*8+j]; B-frag: B[k=quad*8+j][n=lane&15] (wt stored
// n-major so the frag is one b128); C/D: col=lane&15, row=quad*4+reg (m89).
__global__ __launch_bounds__(256) void gemm_alpha(
    const void* __restrict__ xin, int x_is_bf16,
    const float* __restrict__ W,
    const float* __restrict__ a_src, const float* __restrict__ a_dst,
    unsigned short* __restrict__ hb, float* __restrict__ asrc,
    float* __restrict__ adst, int N) {
    __shared__ union {
        struct { unsigned short xs[64 * LDK]; unsigned short wt[64 * LDK]; } s;
        float cs[64 * LDC];
    } u;
    const int tid = threadIdx.x;
    const int r0 = blockIdx.x * 64;

    // stage W[k][n] -> wt[n][k] bf16 (transposed, n-major)
    for (int i = tid; i < 1024; i += 256) {
        const int k = i >> 4, n0 = (i & 15) * 4;
        const float4 w4 = *(const float4*)&W[k * 64 + n0];
        u.s.wt[(n0 + 0) * LDK + k] = f2bf(w4.x);
        u.s.wt[(n0 + 1) * LDK + k] = f2bf(w4.y);
        u.s.wt[(n0 + 2) * LDK + k] = f2bf(w4.z);
        u.s.wt[(n0 + 3) * LDK + k] = f2bf(w4.w);
    }
    // stage x rows -> xs[r][k] bf16
    if (x_is_bf16) {
        const unsigned short* xb = (const unsigned short*)xin;
        for (int i = tid; i < 1024; i += 256) {
            const int r = i >> 4, c0 = (i & 15) * 4;
            const int gr = r0 + r;
            uint2 v = make_uint2(0u, 0u);
            if (gr < N) v = *(const uint2*)&xb[(size_t)gr * D + c0];
            *(uint2*)&u.s.xs[r * LDK + c0] = v;
        }
    } else {
        const float* xf = (const float*)xin;
        for (int i = tid; i < 1024; i += 256) {
            const int r = i >> 4, c0 = (i & 15) * 4;
            const int gr = r0 + r;
            float4 v = make_float4(0.f, 0.f, 0.f, 0.f);
            if (gr < N) v = *(const float4*)&xf[(size_t)gr * D + c0];
            unsigned short q[4] = {f2bf(v.x), f2bf(v.y), f2bf(v.z), f2bf(v.w)};
            *(uint2*)&u.s.xs[r * LDK + c0] = *(uint2*)q;
        }
    }
    __syncthreads();

    const int wv = tid >> 6, lane = tid & 63;
    const int m = lane & 15, quad = lane >> 4;
    const int rw = wv * 16;
    bf16x8 afr0 = *(const bf16x8*)&u.s.xs[(rw + m) * LDK + quad * 8];
    bf16x8 afr1 = *(const bf16x8*)&u.s.xs[(rw + m) * LDK + 32 + quad * 8];
    f32x4 acc[4];
#pragma unroll
    for (int nt = 0; nt < 4; ++nt) {
        f32x4 a = {0.f, 0.f, 0.f, 0.f};
        const bf16x8 b0 = *(const bf16x8*)&u.s.wt[(nt * 16 + m) * LDK + quad * 8];
        const bf16x8 b1 = *(const bf16x8*)&u.s.wt[(nt * 16 + m) * LDK + 32 + quad * 8];
        a = __builtin_amdgcn_mfma_f32_16x16x32_bf16(afr0, b0, a, 0, 0, 0);
        a = __builtin_amdgcn_mfma_f32_16x16x32_bf16(afr1, b1, a, 0, 0, 0);
        acc[nt] = a;
    }
    __syncthreads();  // staging dead; reuse union as C tile
#pragma unroll
    for (int nt = 0; nt < 4; ++nt)
#pragma unroll
        for (int reg = 0; reg < 4; ++reg)
            u.cs[(rw + quad * 4 + reg) * LDC + nt * 16 + m] = acc[nt][reg];
    __syncthreads();

    // epilogue: thread -> row r=tid>>2, 16-col segment; coalesced bf16 store + alpha dots
    {
        const int r = tid >> 2, cseg = (tid & 3) * 16;
        const int gr = r0 + r;
        float vals[16];
#pragma unroll
        for (int q4 = 0; q4 < 4; ++q4)
            *(float4*)&vals[q4 * 4] = *(const float4*)&u.cs[r * LDC + cseg + q4 * 4];
        if (gr < N) {
            unsigned pk[8];
#pragma unroll
            for (int j = 0; j < 8; ++j)
                pk[j] = (unsigned)f2bf(vals[2 * j]) | ((unsigned)f2bf(vals[2 * j + 1]) << 16);
            *(uint4*)&hb[(size_t)gr * D + cseg] = *(uint4*)&pk[0];
            *(uint4*)&hb[(size_t)gr * D + cseg + 8] = *(uint4*)&pk[4];
        }
        float ps = 0.f, pd = 0.f;
#pragma unroll
        for (int q4 = 0; q4 < 4; ++q4) {
            const float4 as4 = *(const float4*)&a_src[cseg + q4 * 4];
            const float4 ad4 = *(const float4*)&a_dst[cseg + q4 * 4];
            ps = fmaf(vals[q4 * 4 + 0], as4.x, ps); pd = fmaf(vals[q4 * 4 + 0], ad4.x, pd);
            ps = fmaf(vals[q4 * 4 + 1], as4.y, ps); pd = fmaf(vals[q4 * 4 + 1], ad4.y, pd);
            ps = fmaf(vals[q4 * 4 + 2], as4.z, ps); pd = fmaf(vals[q4 * 4 + 2], ad4.z, pd);
            ps = fmaf(vals[q4 * 4 + 3], as4.w, ps); pd = fmaf(vals[q4 * 4 + 3], ad4.w, pd);
        }
        ps += __shfl_xor(ps, 1); ps += __shfl_xor(ps, 2);
        pd += __shfl_xor(pd, 1); pd += __shfl_xor(pd, 2);
        if ((tid & 3) == 0 && gr < N) { asrc[gr] = ps; adst[gr] = pd; }
    }
}

// A.1: per-tile histogram over coarse buckets (d>>7). mat[b*nblkA + blk] = count.
__global__ void histA(const int* __restrict__ dst, int* __restrict__ mat,
                      int E, int nblkA, int NBc) {
    __shared__ int cnt[1024];
    for (int b = threadIdx.x; b < NBc; b += 256) cnt[b] = 0;
    __syncthreads();
    const int base = blockIdx.x * TILE;
    for (int j = threadIdx.x; j < TILE; j += 256) {
        int i = base + j;
        if (i < E) atomicAdd(&cnt[dst[i] >> 7], 1);
    }
    __syncthreads();
    for (int b = threadIdx.x; b < NBc; b += 256) mat[b * nblkA + blockIdx.x] = cnt[b];
}

// A.2: hierarchical exclusive scan of mat[0..M) in place (bucket-major).
__global__ void scan_part1(const int* __restrict__ a, int* __restrict__ bsum, int M) {
    __shared__ int s[4];
    const int lane = threadIdx.x & 63, wid = threadIdx.x >> 6;
    int base = blockIdx.x * 1024;
    int v = 0;
    for (int j = threadIdx.x; j < 1024; j += 256) {
        int i = base + j;
        v += (i < M) ? a[i] : 0;
    }
#pragma unroll
    for (int off = 32; off; off >>= 1) v += __shfl_xor(v, off);
    if (lane == 0) s[wid] = v;
    __syncthreads();
    if (threadIdx.x == 0) bsum[blockIdx.x] = s[0] + s[1] + s[2] + s[3];
}
__global__ void scan_part2(int* __restrict__ bsum, int nb) {
    const int lane = threadIdx.x;  // 64 threads
    int running = 0;
    for (int base = 0; base < nb; base += 64) {
        int i = base + lane;
        int v = (i < nb) ? bsum[i] : 0;
        int x = v;
#pragma unroll
        for (int off = 1; off < 64; off <<= 1) {
            int y = __shfl_up(x, off);
            if (lane >= off) x += y;
        }
        if (i < nb) bsum[i] = running + x - v;
        running += __shfl(x, 63);
    }
}
__global__ void scan_part3(int* __restrict__ a, const int* __restrict__ bsum, int M) {
    __shared__ int wsum[4];
    const int lane = threadIdx.x & 63, wid = threadIdx.x >> 6;
    const int i0 = blockIdx.x * 1024 + (int)threadIdx.x * 4;
    int v[4];
#pragma unroll
    for (int u = 0; u < 4; ++u) v[u] = (i0 + u < M) ? a[i0 + u] : 0;
    int tsum = v[0] + v[1] + v[2] + v[3];
    int incl = tsum;
#pragma unroll
    for (int off = 1; off < 64; off <<= 1) {
        int y = __shfl_up(incl, off);
        if (lane >= off) incl += y;
    }
    if (lane == 63) wsum[wid] = incl;
    __syncthreads();
    int woff = 0;
    for (int w = 0; w < wid; ++w) woff += wsum[w];
    int ex = bsum[blockIdx.x] + woff + incl - tsum;
#pragma unroll
    for (int u = 0; u < 4; ++u) {
        if (i0 + u < M) a[i0 + u] = ex;
        ex += v[u];
    }
}

// A.3: replay tile; write packed (d&127)<<17 | src into this block's contiguous
// per-bucket allocation (LDS cursors from scanned mat column).
__global__ void scatterA(const int* __restrict__ src, const int* __restrict__ dst,
                         const int* __restrict__ mat, unsigned* __restrict__ tmp,
                         int E, int nblkA, int NBc) {
    __shared__ int cur[1024];
    for (int b = threadIdx.x; b < NBc; b += 256) cur[b] = mat[b * nblkA + blockIdx.x];
    __syncthreads();
    const int base = blockIdx.x * TILE;
    for (int j = threadIdx.x; j < TILE; j += 256) {
        int i = base + j;
        if (i < E) {
            int d = dst[i];
            int pos = atomicAdd(&cur[d >> 7], 1);
            tmp[pos] = ((unsigned)(d & (BKT - 1)) << 17) | (unsigned)src[i];
        }
    }
}

// B: one block per coarse bucket (128 nodes). Builds row[] and places src into csr.
__global__ void bucket_build(const int* __restrict__ mat, const unsigned* __restrict__ tmp,
                             int* __restrict__ row, int* __restrict__ csr,
                             int N, int E, int nblkA, int NBc) {
    __shared__ int cnt[BKT];
    __shared__ int cur[BKT];
    __shared__ int wsumS[2];
    const int b = blockIdx.x;
    const int n0 = b << 7;
    const int tid = threadIdx.x;
    const int beg = mat[b * nblkA];
    const int end = (b + 1 < NBc) ? mat[(b + 1) * nblkA] : E;
    if (tid < BKT) cnt[tid] = 0;
    __syncthreads();
    for (int i = beg + tid; i < end; i += 256) atomicAdd(&cnt[tmp[i] >> 17], 1);
    __syncthreads();
    int v = (tid < BKT) ? cnt[tid] : 0;
    int x = v;
#pragma unroll
    for (int off = 1; off < 64; off <<= 1) {
        int y = __shfl_up(x, off);
        if ((tid & 63) >= off) x += y;
    }
    if (tid < BKT && (tid & 63) == 63) wsumS[tid >> 6] = x;
    __syncthreads();
    const int add = (tid >= 64 && tid < BKT) ? wsumS[0] : 0;
    const int ex = beg + add + x - v;
    if (tid < BKT) {
        const int node = n0 + tid;
        if (node < N) row[node] = ex;
        cur[tid] = ex;
    }
    if (b == NBc - 1 && tid == 0) row[N] = E;
    __syncthreads();
    for (int i = beg + tid; i < end; i += 256) {
        unsigned e = tmp[i];
        int pos = atomicAdd(&cur[e >> 17], 1);
        csr[pos] = (int)(e & 0x1FFFFu);
    }
}

// Aggregate: one node per 8-lane group (32 nodes/block). Lane owns 8 features.
// Group-uniform csr/asrc loads, weight computed once per edge, dnp replicated ->
// no cross-lane reductions. out_bf16: layer-1 writes x1 as bf16 (gemm2 A input).
__global__ __launch_bounds__(256) void aggregate(
    const int* __restrict__ row, const int* __restrict__ csr_src,
    const float* __restrict__ asrc, const float* __restrict__ adst,
    const unsigned short* __restrict__ hb, const float* __restrict__ bias,
    void* __restrict__ outp, int N, int do_elu, int out_bf16) {
    const int g = threadIdx.x >> 3;
    const int c = threadIdx.x & 7;
    const int d = blockIdx.x * 32 + g;
    if (d >= N) return;
    const int beg = row[d], end = row[d + 1];
    const float ad = adst[d];
    float dnp = __expf(lrelu(asrc[d] + ad));

    const unsigned short* hrow = hb + (c << 3);
    float acc[8];
    {
        const uint4 hv = *(const uint4*)(hrow + ((unsigned)d << 6));
        float2 p;
        p = bf2f2(hv.x); acc[0] = dnp * p.x; acc[1] = dnp * p.y;
        p = bf2f2(hv.y); acc[2] = dnp * p.x; acc[3] = dnp * p.y;
        p = bf2f2(hv.z); acc[4] = dnp * p.x; acc[5] = dnp * p.y;
        p = bf2f2(hv.w); acc[6] = dnp * p.x; acc[7] = dnp * p.y;
    }

    int i = beg;
    for (; i + 2 <= end; i += 2) {
        const int s0 = csr_src[i], s1 = csr_src[i + 1];
        const float a0 = asrc[s0], a1 = asrc[s1];
        const uint4 h0 = *(const uint4*)(hrow + ((unsigned)s0 << 6));
        const uint4 h1 = *(const uint4*)(hrow + ((unsigned)s1 << 6));
        const float w0 = __expf(lrelu(a0 + ad));
        const float w1 = __expf(lrelu(a1 + ad));
        dnp += w0 + w1;
        float2 p;
        p = bf2f2(h0.x); acc[0] = fmaf(w0, p.x, acc[0]); acc[1] = fmaf(w0, p.y, acc[1]);
        p = bf2f2(h0.y); acc[2] = fmaf(w0, p.x, acc[2]); acc[3] = fmaf(w0, p.y, acc[3]);
        p = bf2f2(h0.z); acc[4] = fmaf(w0, p.x, acc[4]); acc[5] = fmaf(w0, p.y, acc[5]);
        p = bf2f2(h0.w); acc[6] = fmaf(w0, p.x, acc[6]); acc[7] = fmaf(w0, p.y, acc[7]);
        p = bf2f2(h1.x); acc[0] = fmaf(w1, p.x, acc[0]); acc[1] = fmaf(w1, p.y, acc[1]);
        p = bf2f2(h1.y); acc[2] = fmaf(w1, p.x, acc[2]); acc[3] = fmaf(w1, p.y, acc[3]);
        p = bf2f2(h1.z); acc[4] = fmaf(w1, p.x, acc[4]); acc[5] = fmaf(w1, p.y, acc[5]);
        p = bf2f2(h1.w); acc[6] = fmaf(w1, p.x, acc[6]); acc[7] = fmaf(w1, p.y, acc[7]);
    }
    if (i < end) {
        const int s0 = csr_src[i];
        const float w0 = __expf(lrelu(asrc[s0] + ad));
        const uint4 h0 = *(const uint4*)(hrow + ((unsigned)s0 << 6));
        dnp += w0;
        float2 p;
        p = bf2f2(h0.x); acc[0] = fmaf(w0, p.x, acc[0]); acc[1] = fmaf(w0, p.y, acc[1]);
        p = bf2f2(h0.y); acc[2] = fmaf(w0, p.x, acc[2]); acc[3] = fmaf(w0, p.y, acc[3]);
        p = bf2f2(h0.z); acc[4] = fmaf(w0, p.x, acc[4]); acc[5] = fmaf(w0, p.y, acc[5]);
        p = bf2f2(h0.w); acc[6] = fmaf(w0, p.x, acc[6]); acc[7] = fmaf(w0, p.y, acc[7]);
    }

    const float inv = 1.f / dnp;
    const float4 b0 = *(const float4*)&bias[c << 3];
    const float4 b1 = *(const float4*)&bias[(c << 3) + 4];
    float v[8];
    v[0] = fmaf(acc[0], inv, b0.x); v[1] = fmaf(acc[1], inv, b0.y);
    v[2] = fmaf(acc[2], inv, b0.z); v[3] = fmaf(acc[3], inv, b0.w);
    v[4] = fmaf(acc[4], inv, b1.x); v[5] = fmaf(acc[5], inv, b1.y);
    v[6] = fmaf(acc[6], inv, b1.z); v[7] = fmaf(acc[7], inv, b1.w);
    if (do_elu) {
#pragma unroll
        for (int k = 0; k < 8; ++k) v[k] = v[k] > 0.f ? v[k] : expm1f(v[k]);
    }
    if (out_bf16) {
        unsigned pk[4];
#pragma unroll
        for (int j = 0; j < 4; ++j)
            pk[j] = (unsigned)f2bf(v[2 * j]) | ((unsigned)f2bf(v[2 * j + 1]) << 16);
        *(uint4*)((unsigned short*)outp + ((size_t)d << 6) + (c << 3)) = *(uint4*)pk;
    } else {
        float* out = (float*)outp;
        *(float4*)&out[((size_t)d << 6) + (c << 3)]     = *(float4*)&v[0];
        *(float4*)&out[((size_t)d << 6) + (c << 3) + 4] = *(float4*)&v[4];
    }
}

extern "C" void kernel_launch(void* const* d_in, const int* in_sizes, int n_in,
                              void* d_out, int out_size, void* d_ws, size_t ws_size,
                              hipStream_t stream) {
    const int*   eidx = (const int*)d_in[0];
    const float* emb  = (const float*)d_in[1];
    const float* W1   = (const float*)d_in[2];
    const float* a1s  = (const float*)d_in[3];
    const float* a1d  = (const float*)d_in[4];
    const float* b1   = (const float*)d_in[5];
    const float* W2   = (const float*)d_in[6];
    const float* a2s  = (const float*)d_in[7];
    const float* a2d  = (const float*)d_in[8];
    const float* b2   = (const float*)d_in[9];
    float* out = (float*)d_out;

    const int E = in_sizes[0] / 2;
    const int N = in_sizes[1] / D;  // requires N <= 131072 (17-bit src packing)
    const int* src = eidx;
    const int* dst = eidx + E;

    const int nblkA = (E + TILE - 1) / TILE;
    const int NBc   = (N + BKT - 1) / BKT;
    const int M     = NBc * nblkA;
    const int nscan = (M + 1023) / 1024;

    // Workspace: hb [N*D bf16], x1b [N*D bf16], asrc/adst [N], row [N+1],
    // mat [M], msum [nscan], csr [E]. tmp [E] aliases x1b (dead until L1 aggregate).
    unsigned short* hb  = (unsigned short*)d_ws;
    unsigned short* x1b = hb + (size_t)N * D;
    float* asrc = (float*)(x1b + (size_t)N * D);
    float* adst = asrc + N;
    int* row    = (int*)(adst + N);
    int* mat    = row + N + 1;
    int* msum   = mat + M;
    int* csr    = msum + nscan;
    unsigned* tmp = (unsigned*)x1b;

    const int gemmBlocks = (N + 63) / 64;
    const int aggBlocks  = (N + 31) / 32;

    // ---- CSR build ----
    histA<<<nblkA, 256, 0, stream>>>(dst, mat, E, nblkA, NBc);
    scan_part1<<<nscan, 256, 0, stream>>>(mat, msum, M);
    scan_part2<<<1, 64, 0, stream>>>(msum, nscan);
    scan_part3<<<nscan, 256, 0, stream>>>(mat, msum, M);
    scatterA<<<nblkA, 256, 0, stream>>>(src, dst, mat, tmp, E, nblkA, NBc);
    bucket_build<<<NBc, 256, 0, stream>>>(mat, tmp, row, csr, N, E, nblkA, NBc);

    // ---- Layer 1 ----
    gemm_alpha<<<gemmBlocks, 256, 0, stream>>>(emb, 0, W1, a1s, a1d, hb, asrc, adst, N);
    aggregate<<<aggBlocks, 256, 0, stream>>>(row, csr, asrc, adst, hb, b1, x1b, N, 1, 1);

    // ---- Layer 2 ----
    gemm_alpha<<<gemmBlocks, 256, 0, stream>>>(x1b, 1, W2, a2s, a2d, hb, asrc, adst, N);
    aggregate<<<aggBlocks, 256, 0, stream>>>(row, csr, asrc, adst, hb, b2, out, N, 0, 0);
}

// Round 10
// 264.396 us; speedup vs baseline: 1.5318x; 1.0116x over previous
//
#include <hip/hip_runtime.h>
#include <math.h>

#define D 64
#define NEG_SLOPE 0.2f
#define TILE 2048   // edges per partition block (782 blocks at E=1.6M)
#define BKT 128     // nodes per coarse bucket
#define LDK 72      // padded k-stride (bf16 elems) for MFMA LDS tiles
#define LDC 72      // padded col-stride (fp32) for epilogue C tile

typedef __attribute__((ext_vector_type(8))) short bf16x8;
typedef __attribute__((ext_vector_type(4))) float f32x4;

__device__ __forceinline__ float lrelu(float x) { return fmaxf(x, NEG_SLOPE * x); }

// fp32 -> bf16 round-to-nearest-even.
__device__ __forceinline__ unsigned short f2bf(float f) {
    unsigned u = __float_as_uint(f);
    return (unsigned short)((u + 0x7fffu + ((u >> 16) & 1u)) >> 16);
}
__device__ __forceinline__ float2 bf2f2(unsigned u) {
    float2 r;
    r.x = __uint_as_float(u << 16);
    r.y = __uint_as_float(u & 0xffff0000u);
    return r;
}

// MFMA bf16 GEMM: h_bf16 = bf16(x @ W) + fused alpha_src/alpha_dst dot products.
// Block: 64 rows x 64 cols, 4 waves; wave w owns rows w*16..+15 (4 n-tiles x K=64).
__global__ __launch_bounds__(256) void gemm_alpha(
    const void* __restrict__ xin, int x_is_bf16,
    const float* __restrict__ W,
    const float* __restrict__ a_src, const float* __restrict__ a_dst,
    unsigned short* __restrict__ hb, float* __restrict__ asrc,
    float* __restrict__ adst, int N) {
    __shared__ union {
        struct { unsigned short xs[64 * LDK]; unsigned short wt[64 * LDK]; } s;
        float cs[64 * LDC];
    } u;
    const int tid = threadIdx.x;
    const int r0 = blockIdx.x * 64;

    // stage W[k][n] -> wt[n][k] bf16 (transposed, n-major)
    for (int i = tid; i < 1024; i += 256) {
        const int k = i >> 4, n0 = (i & 15) * 4;
        const float4 w4 = *(const float4*)&W[k * 64 + n0];
        u.s.wt[(n0 + 0) * LDK + k] = f2bf(w4.x);
        u.s.wt[(n0 + 1) * LDK + k] = f2bf(w4.y);
        u.s.wt[(n0 + 2) * LDK + k] = f2bf(w4.z);
        u.s.wt[(n0 + 3) * LDK + k] = f2bf(w4.w);
    }
    // stage x rows -> xs[r][k] bf16
    if (x_is_bf16) {
        const unsigned short* xb = (const unsigned short*)xin;
        for (int i = tid; i < 1024; i += 256) {
            const int r = i >> 4, c0 = (i & 15) * 4;
            const int gr = r0 + r;
            uint2 v = make_uint2(0u, 0u);
            if (gr < N) v = *(const uint2*)&xb[(size_t)gr * D + c0];
            *(uint2*)&u.s.xs[r * LDK + c0] = v;
        }
    } else {
        const float* xf = (const float*)xin;
        for (int i = tid; i < 1024; i += 256) {
            const int r = i >> 4, c0 = (i & 15) * 4;
            const int gr = r0 + r;
            float4 v = make_float4(0.f, 0.f, 0.f, 0.f);
            if (gr < N) v = *(const float4*)&xf[(size_t)gr * D + c0];
            unsigned short q[4] = {f2bf(v.x), f2bf(v.y), f2bf(v.z), f2bf(v.w)};
            *(uint2*)&u.s.xs[r * LDK + c0] = *(uint2*)q;
        }
    }
    __syncthreads();

    const int wv = tid >> 6, lane = tid & 63;
    const int m = lane & 15, quad = lane >> 4;
    const int rw = wv * 16;
    bf16x8 afr0 = *(const bf16x8*)&u.s.xs[(rw + m) * LDK + quad * 8];
    bf16x8 afr1 = *(const bf16x8*)&u.s.xs[(rw + m) * LDK + 32 + quad * 8];
    f32x4 acc[4];
#pragma unroll
    for (int nt = 0; nt < 4; ++nt) {
        f32x4 a = {0.f, 0.f, 0.f, 0.f};
        const bf16x8 b0 = *(const bf16x8*)&u.s.wt[(nt * 16 + m) * LDK + quad * 8];
        const bf16x8 b1 = *(const bf16x8*)&u.s.wt[(nt * 16 + m) * LDK + 32 + quad * 8];
        a = __builtin_amdgcn_mfma_f32_16x16x32_bf16(afr0, b0, a, 0, 0, 0);
        a = __builtin_amdgcn_mfma_f32_16x16x32_bf16(afr1, b1, a, 0, 0, 0);
        acc[nt] = a;
    }
    __syncthreads();  // staging dead; reuse union as C tile
#pragma unroll
    for (int nt = 0; nt < 4; ++nt)
#pragma unroll
        for (int reg = 0; reg < 4; ++reg)
            u.cs[(rw + quad * 4 + reg) * LDC + nt * 16 + m] = acc[nt][reg];
    __syncthreads();

    // epilogue: thread -> row r=tid>>2, 16-col segment; coalesced bf16 store + alpha dots
    {
        const int r = tid >> 2, cseg = (tid & 3) * 16;
        const int gr = r0 + r;
        float vals[16];
#pragma unroll
        for (int q4 = 0; q4 < 4; ++q4)
            *(float4*)&vals[q4 * 4] = *(const float4*)&u.cs[r * LDC + cseg + q4 * 4];
        if (gr < N) {
            unsigned pk[8];
#pragma unroll
            for (int j = 0; j < 8; ++j)
                pk[j] = (unsigned)f2bf(vals[2 * j]) | ((unsigned)f2bf(vals[2 * j + 1]) << 16);
            *(uint4*)&hb[(size_t)gr * D + cseg] = *(uint4*)&pk[0];
            *(uint4*)&hb[(size_t)gr * D + cseg + 8] = *(uint4*)&pk[4];
        }
        float ps = 0.f, pd = 0.f;
#pragma unroll
        for (int q4 = 0; q4 < 4; ++q4) {
            const float4 as4 = *(const float4*)&a_src[cseg + q4 * 4];
            const float4 ad4 = *(const float4*)&a_dst[cseg + q4 * 4];
            ps = fmaf(vals[q4 * 4 + 0], as4.x, ps); pd = fmaf(vals[q4 * 4 + 0], ad4.x, pd);
            ps = fmaf(vals[q4 * 4 + 1], as4.y, ps); pd = fmaf(vals[q4 * 4 + 1], ad4.y, pd);
            ps = fmaf(vals[q4 * 4 + 2], as4.z, ps); pd = fmaf(vals[q4 * 4 + 2], ad4.z, pd);
            ps = fmaf(vals[q4 * 4 + 3], as4.w, ps); pd = fmaf(vals[q4 * 4 + 3], ad4.w, pd);
        }
        ps += __shfl_xor(ps, 1); ps += __shfl_xor(ps, 2);
        pd += __shfl_xor(pd, 1); pd += __shfl_xor(pd, 2);
        if ((tid & 3) == 0 && gr < N) { asrc[gr] = ps; adst[gr] = pd; }
    }
}

// A.1: per-tile histogram over coarse buckets (d>>7). mat[b*nblkA + blk] = count.
__global__ void histA(const int* __restrict__ dst, int* __restrict__ mat,
                      int E, int nblkA, int NBc) {
    __shared__ int cnt[1024];
    for (int b = threadIdx.x; b < NBc; b += 256) cnt[b] = 0;
    __syncthreads();
    const int base = blockIdx.x * TILE;
    for (int j = threadIdx.x; j < TILE; j += 256) {
        int i = base + j;
        if (i < E) atomicAdd(&cnt[dst[i] >> 7], 1);
    }
    __syncthreads();
    for (int b = threadIdx.x; b < NBc; b += 256) mat[b * nblkA + blockIdx.x] = cnt[b];
}

// A.2: hierarchical exclusive scan of mat[0..M) in place (bucket-major).
__global__ void scan_part1(const int* __restrict__ a, int* __restrict__ bsum, int M) {
    __shared__ int s[4];
    const int lane = threadIdx.x & 63, wid = threadIdx.x >> 6;
    int base = blockIdx.x * 1024;
    int v = 0;
    for (int j = threadIdx.x; j < 1024; j += 256) {
        int i = base + j;
        v += (i < M) ? a[i] : 0;
    }
#pragma unroll
    for (int off = 32; off; off >>= 1) v += __shfl_xor(v, off);
    if (lane == 0) s[wid] = v;
    __syncthreads();
    if (threadIdx.x == 0) bsum[blockIdx.x] = s[0] + s[1] + s[2] + s[3];
}
__global__ void scan_part2(int* __restrict__ bsum, int nb) {
    const int lane = threadIdx.x;  // 64 threads
    int running = 0;
    for (int base = 0; base < nb; base += 64) {
        int i = base + lane;
        int v = (i < nb) ? bsum[i] : 0;
        int x = v;
#pragma unroll
        for (int off = 1; off < 64; off <<= 1) {
            int y = __shfl_up(x, off);
            if (lane >= off) x += y;
        }
        if (i < nb) bsum[i] = running + x - v;
        running += __shfl(x, 63);
    }
}
__global__ void scan_part3(int* __restrict__ a, const int* __restrict__ bsum, int M) {
    __shared__ int wsum[4];
    const int lane = threadIdx.x & 63, wid = threadIdx.x >> 6;
    const int i0 = blockIdx.x * 1024 + (int)threadIdx.x * 4;
    int v[4];
#pragma unroll
    for (int u = 0; u < 4; ++u) v[u] = (i0 + u < M) ? a[i0 + u] : 0;
    int tsum = v[0] + v[1] + v[2] + v[3];
    int incl = tsum;
#pragma unroll
    for (int off = 1; off < 64; off <<= 1) {
        int y = __shfl_up(incl, off);
        if (lane >= off) incl += y;
    }
    if (lane == 63) wsum[wid] = incl;
    __syncthreads();
    int woff = 0;
    for (int w = 0; w < wid; ++w) woff += wsum[w];
    int ex = bsum[blockIdx.x] + woff + incl - tsum;
#pragma unroll
    for (int u = 0; u < 4; ++u) {
        if (i0 + u < M) a[i0 + u] = ex;
        ex += v[u];
    }
}

// A.3: replay tile; write packed (d&127)<<17 | src into this block's contiguous
// per-bucket allocation (LDS cursors from scanned mat column).
__global__ void scatterA(const int* __restrict__ src, const int* __restrict__ dst,
                         const int* __restrict__ mat, unsigned* __restrict__ tmp,
                         int E, int nblkA, int NBc) {
    __shared__ int cur[1024];
    for (int b = threadIdx.x; b < NBc; b += 256) cur[b] = mat[b * nblkA + blockIdx.x];
    __syncthreads();
    const int base = blockIdx.x * TILE;
    for (int j = threadIdx.x; j < TILE; j += 256) {
        int i = base + j;
        if (i < E) {
            int d = dst[i];
            int pos = atomicAdd(&cur[d >> 7], 1);
            tmp[pos] = ((unsigned)(d & (BKT - 1)) << 17) | (unsigned)src[i];
        }
    }
}

// B: one block per coarse bucket (128 nodes). Builds row[] and places src into csr.
__global__ void bucket_build(const int* __restrict__ mat, const unsigned* __restrict__ tmp,
                             int* __restrict__ row, int* __restrict__ csr,
                             int N, int E, int nblkA, int NBc) {
    __shared__ int cnt[BKT];
    __shared__ int cur[BKT];
    __shared__ int wsumS[2];
    const int b = blockIdx.x;
    const int n0 = b << 7;
    const int tid = threadIdx.x;
    const int beg = mat[b * nblkA];
    const int end = (b + 1 < NBc) ? mat[(b + 1) * nblkA] : E;
    if (tid < BKT) cnt[tid] = 0;
    __syncthreads();
    for (int i = beg + tid; i < end; i += 256) atomicAdd(&cnt[tmp[i] >> 17], 1);
    __syncthreads();
    int v = (tid < BKT) ? cnt[tid] : 0;
    int x = v;
#pragma unroll
    for (int off = 1; off < 64; off <<= 1) {
        int y = __shfl_up(x, off);
        if ((tid & 63) >= off) x += y;
    }
    if (tid < BKT && (tid & 63) == 63) wsumS[tid >> 6] = x;
    __syncthreads();
    const int add = (tid >= 64 && tid < BKT) ? wsumS[0] : 0;
    const int ex = beg + add + x - v;
    if (tid < BKT) {
        const int node = n0 + tid;
        if (node < N) row[node] = ex;
        cur[tid] = ex;
    }
    if (b == NBc - 1 && tid == 0) row[N] = E;
    __syncthreads();
    for (int i = beg + tid; i < end; i += 256) {
        unsigned e = tmp[i];
        int pos = atomicAdd(&cur[e >> 17], 1);
        csr[pos] = (int)(e & 0x1FFFFu);
    }
}

// Aggregate: one node per 8-lane group (32 nodes/block). Lane owns 8 features.
// Unroll-4 with hoisted loads: 4 csr reads, then 4 asrc + 4 hb-row loads issued
// before any exp/FMA -> 2x loads-in-flight vs unroll-2 (kernel is latency-bound:
// logical 218 MB but only ~13 us of BW service; dependent csr->asrc/hb chain).
__global__ __launch_bounds__(256) void aggregate(
    const int* __restrict__ row, const int* __restrict__ csr_src,
    const float* __restrict__ asrc, const float* __restrict__ adst,
    const unsigned short* __restrict__ hb, const float* __restrict__ bias,
    void* __restrict__ outp, int N, int do_elu, int out_bf16) {
    const int g = threadIdx.x >> 3;
    const int c = threadIdx.x & 7;
    const int d = blockIdx.x * 32 + g;
    if (d >= N) return;
    const int beg = row[d], end = row[d + 1];
    const float ad = adst[d];
    float dnp = __expf(lrelu(asrc[d] + ad));

    const unsigned short* hrow = hb + (c << 3);
    float acc[8];
    {
        const uint4 hv = *(const uint4*)(hrow + ((unsigned)d << 6));
        float2 p;
        p = bf2f2(hv.x); acc[0] = dnp * p.x; acc[1] = dnp * p.y;
        p = bf2f2(hv.y); acc[2] = dnp * p.x; acc[3] = dnp * p.y;
        p = bf2f2(hv.z); acc[4] = dnp * p.x; acc[5] = dnp * p.y;
        p = bf2f2(hv.w); acc[6] = dnp * p.x; acc[7] = dnp * p.y;
    }

    int i = beg;
    for (; i + 4 <= end; i += 4) {
        const int s0 = csr_src[i], s1 = csr_src[i + 1];
        const int s2 = csr_src[i + 2], s3 = csr_src[i + 3];
        const float a0 = asrc[s0], a1 = asrc[s1], a2 = asrc[s2], a3 = asrc[s3];
        const uint4 h0 = *(const uint4*)(hrow + ((unsigned)s0 << 6));
        const uint4 h1 = *(const uint4*)(hrow + ((unsigned)s1 << 6));
        const uint4 h2 = *(const uint4*)(hrow + ((unsigned)s2 << 6));
        const uint4 h3 = *(const uint4*)(hrow + ((unsigned)s3 << 6));
        const float w0 = __expf(lrelu(a0 + ad));
        const float w1 = __expf(lrelu(a1 + ad));
        const float w2 = __expf(lrelu(a2 + ad));
        const float w3 = __expf(lrelu(a3 + ad));
        dnp += (w0 + w1) + (w2 + w3);
        float2 p;
        p = bf2f2(h0.x); acc[0] = fmaf(w0, p.x, acc[0]); acc[1] = fmaf(w0, p.y, acc[1]);
        p = bf2f2(h0.y); acc[2] = fmaf(w0, p.x, acc[2]); acc[3] = fmaf(w0, p.y, acc[3]);
        p = bf2f2(h0.z); acc[4] = fmaf(w0, p.x, acc[4]); acc[5] = fmaf(w0, p.y, acc[5]);
        p = bf2f2(h0.w); acc[6] = fmaf(w0, p.x, acc[6]); acc[7] = fmaf(w0, p.y, acc[7]);
        p = bf2f2(h1.x); acc[0] = fmaf(w1, p.x, acc[0]); acc[1] = fmaf(w1, p.y, acc[1]);
        p = bf2f2(h1.y); acc[2] = fmaf(w1, p.x, acc[2]); acc[3] = fmaf(w1, p.y, acc[3]);
        p = bf2f2(h1.z); acc[4] = fmaf(w1, p.x, acc[4]); acc[5] = fmaf(w1, p.y, acc[5]);
        p = bf2f2(h1.w); acc[6] = fmaf(w1, p.x, acc[6]); acc[7] = fmaf(w1, p.y, acc[7]);
        p = bf2f2(h2.x); acc[0] = fmaf(w2, p.x, acc[0]); acc[1] = fmaf(w2, p.y, acc[1]);
        p = bf2f2(h2.y); acc[2] = fmaf(w2, p.x, acc[2]); acc[3] = fmaf(w2, p.y, acc[3]);
        p = bf2f2(h2.z); acc[4] = fmaf(w2, p.x, acc[4]); acc[5] = fmaf(w2, p.y, acc[5]);
        p = bf2f2(h2.w); acc[6] = fmaf(w2, p.x, acc[6]); acc[7] = fmaf(w2, p.y, acc[7]);
        p = bf2f2(h3.x); acc[0] = fmaf(w3, p.x, acc[0]); acc[1] = fmaf(w3, p.y, acc[1]);
        p = bf2f2(h3.y); acc[2] = fmaf(w3, p.x, acc[2]); acc[3] = fmaf(w3, p.y, acc[3]);
        p = bf2f2(h3.z); acc[4] = fmaf(w3, p.x, acc[4]); acc[5] = fmaf(w3, p.y, acc[5]);
        p = bf2f2(h3.w); acc[6] = fmaf(w3, p.x, acc[6]); acc[7] = fmaf(w3, p.y, acc[7]);
    }
    for (; i < end; ++i) {
        const int s0 = csr_src[i];
        const float w0 = __expf(lrelu(asrc[s0] + ad));
        const uint4 h0 = *(const uint4*)(hrow + ((unsigned)s0 << 6));
        dnp += w0;
        float2 p;
        p = bf2f2(h0.x); acc[0] = fmaf(w0, p.x, acc[0]); acc[1] = fmaf(w0, p.y, acc[1]);
        p = bf2f2(h0.y); acc[2] = fmaf(w0, p.x, acc[2]); acc[3] = fmaf(w0, p.y, acc[3]);
        p = bf2f2(h0.z); acc[4] = fmaf(w0, p.x, acc[4]); acc[5] = fmaf(w0, p.y, acc[5]);
        p = bf2f2(h0.w); acc[6] = fmaf(w0, p.x, acc[6]); acc[7] = fmaf(w0, p.y, acc[7]);
    }

    const float inv = 1.f / dnp;
    const float4 b0 = *(const float4*)&bias[c << 3];
    const float4 b1 = *(const float4*)&bias[(c << 3) + 4];
    float v[8];
    v[0] = fmaf(acc[0], inv, b0.x); v[1] = fmaf(acc[1], inv, b0.y);
    v[2] = fmaf(acc[2], inv, b0.z); v[3] = fmaf(acc[3], inv, b0.w);
    v[4] = fmaf(acc[4], inv, b1.x); v[5] = fmaf(acc[5], inv, b1.y);
    v[6] = fmaf(acc[6], inv, b1.z); v[7] = fmaf(acc[7], inv, b1.w);
    if (do_elu) {
#pragma unroll
        for (int k = 0; k < 8; ++k) v[k] = v[k] > 0.f ? v[k] : expm1f(v[k]);
    }
    if (out_bf16) {
        unsigned pk[4];
#pragma unroll
        for (int j = 0; j < 4; ++j)
            pk[j] = (unsigned)f2bf(v[2 * j]) | ((unsigned)f2bf(v[2 * j + 1]) << 16);
        *(uint4*)((unsigned short*)outp + ((size_t)d << 6) + (c << 3)) = *(uint4*)pk;
    } else {
        float* out = (float*)outp;
        *(float4*)&out[((size_t)d << 6) + (c << 3)]     = *(float4*)&v[0];
        *(float4*)&out[((size_t)d << 6) + (c << 3) + 4] = *(float4*)&v[4];
    }
}

extern "C" void kernel_launch(void* const* d_in, const int* in_sizes, int n_in,
                              void* d_out, int out_size, void* d_ws, size_t ws_size,
                              hipStream_t stream) {
    const int*   eidx = (const int*)d_in[0];
    const float* emb  = (const float*)d_in[1];
    const float* W1   = (const float*)d_in[2];
    const float* a1s  = (const float*)d_in[3];
    const float* a1d  = (const float*)d_in[4];
    const float* b1   = (const float*)d_in[5];
    const float* W2   = (const float*)d_in[6];
    const float* a2s  = (const float*)d_in[7];
    const float* a2d  = (const float*)d_in[8];
    const float* b2   = (const float*)d_in[9];
    float* out = (float*)d_out;

    const int E = in_sizes[0] / 2;
    const int N = in_sizes[1] / D;  // requires N <= 131072 (17-bit src packing)
    const int* src = eidx;
    const int* dst = eidx + E;

    const int nblkA = (E + TILE - 1) / TILE;
    const int NBc   = (N + BKT - 1) / BKT;
    const int M     = NBc * nblkA;
    const int nscan = (M + 1023) / 1024;

    // Workspace: hb [N*D bf16], x1b [N*D bf16], asrc/adst [N], row [N+1],
    // mat [M], msum [nscan], csr [E]. tmp [E] aliases x1b (dead until L1 aggregate).
    unsigned short* hb  = (unsigned short*)d_ws;
    unsigned short* x1b = hb + (size_t)N * D;
    float* asrc = (float*)(x1b + (size_t)N * D);
    float* adst = asrc + N;
    int* row    = (int*)(adst + N);
    int* mat    = row + N + 1;
    int* msum   = mat + M;
    int* csr    = msum + nscan;
    unsigned* tmp = (unsigned*)x1b;

    const int gemmBlocks = (N + 63) / 64;
    const int aggBlocks  = (N + 31) / 32;

    // ---- CSR build ----
    histA<<<nblkA, 256, 0, stream>>>(dst, mat, E, nblkA, NBc);
    scan_part1<<<nscan, 256, 0, stream>>>(mat, msum, M);
    scan_part2<<<1, 64, 0, stream>>>(msum, nscan);
    scan_part3<<<nscan, 256, 0, stream>>>(mat, msum, M);
    scatterA<<<nblkA, 256, 0, stream>>>(src, dst, mat, tmp, E, nblkA, NBc);
    bucket_build<<<NBc, 256, 0, stream>>>(mat, tmp, row, csr, N, E, nblkA, NBc);

    // ---- Layer 1 ----
    gemm_alpha<<<gemmBlocks, 256, 0, stream>>>(emb, 0, W1, a1s, a1d, hb, asrc, adst, N);
    aggregate<<<aggBlocks, 256, 0, stream>>>(row, csr, asrc, adst, hb, b1, x1b, N, 1, 1);

    // ---- Layer 2 ----
    gemm_alpha<<<gemmBlocks, 256, 0, stream>>>(x1b, 1, W2, a2s, a2d, hb, asrc, adst, N);
    aggregate<<<aggBlocks, 256, 0, stream>>>(row, csr, asrc, adst, hb, b2, out, N, 0, 0);
}